// Round 2
// baseline (65.298 us; speedup 1.0000x reference)
//
#include <hip/hip_runtime.h>
#include <math.h>

// GraphPoolMol: B=64, MAX_ATOM=128, N_FEAT=128
// out[b,i,f] = i<n ? max_{j<n, L[b,i,j]!=0} x[b,j,f] (fallback x[b,i,f] if no nbr) : 0
//
// One WAVE per output row. No barriers, no atomics, NO LDS:
//  - L-row nonzero pattern -> two wave-uniform 64-bit ballot masks (SGPRs)
//  - neighbor iteration = scalar ctz / mask&=mask-1 (s_ff1_b64), zero memory
//  - x-row gather: uniform row base (SGPR) + lane*8B, float2 = full 512B row/instr
//  - loop padded to multiple of 4 with the diagonal index (max is idempotent,
//    L[i][i]==1 always) -> every iteration has 4 independent loads in flight

#define MAX_ATOM 128
#define N_FEAT 128
#define B_SIZE 64
#define WAVES_PER_BLOCK 4

__global__ __launch_bounds__(64 * WAVES_PER_BLOCK) void GraphPoolMol_kernel(
    const float* __restrict__ x,       // (B, MAX_ATOM, N_FEAT)
    const float* __restrict__ L,       // (B, MAX_ATOM, MAX_ATOM)
    const int* __restrict__ mol_slice, // (B, 2) -- col 0 = n_atoms
    float* __restrict__ out)           // (B, MAX_ATOM, N_FEAT)
{
    const int lane = threadIdx.x & 63;
    const int w    = threadIdx.x >> 6;                  // wave id within block
    const int i    = blockIdx.x * WAVES_PER_BLOCK + w;  // atom row (wave-uniform)
    const int b    = blockIdx.y;                        // batch

    const int n = mol_slice[b * 2];                     // uniform -> s_load

    float2* __restrict__ orow =
        (float2*)(out + ((size_t)b * MAX_ATOM + i) * N_FEAT);

    if (i >= n) {                                       // padded row: zeros
        orow[lane] = make_float2(0.0f, 0.0f);
        return;                                         // safe: no barriers anywhere
    }

    const float* __restrict__ xb   = x + (size_t)b * MAX_ATOM * N_FEAT;
    const float* __restrict__ Lrow = L + ((size_t)b * MAX_ATOM + i) * MAX_ATOM;

    // ---- nonzero pattern as two wave-uniform 64-bit masks (columns 0-63, 64-127)
    const float l0 = Lrow[lane];                        // coalesced 256B
    const float l1 = Lrow[lane + 64];                   // coalesced 256B
    unsigned long long mask0 = __ballot((lane      < n) && (l0 != 0.0f));
    unsigned long long mask1 = __ballot((lane + 64 < n) && (l1 != 0.0f));

    const int m = __popcll(mask0) + __popcll(mask1);    // >=1: diagonal is 1.0

    // Scalar set-bit iterator; falls back to the diagonal (always a neighbor)
    // when exhausted, so the main loop can always consume groups of 4.
    auto next_j = [&]() -> int {
        if (mask0) {
            const int t = __builtin_ctzll(mask0);
            mask0 &= mask0 - 1;
            return t;
        }
        if (mask1) {
            const int t = __builtin_ctzll(mask1);
            mask1 &= mask1 - 1;
            return t + 64;
        }
        return i;                                       // idempotent pad
    };

    float ax = -INFINITY, ay = -INFINITY;
    for (int k = 0; k < m; k += 4) {                    // ceil(m/4) iters, 4 loads each
        const int ja = next_j();
        const int jb = next_j();
        const int jc = next_j();
        const int jd = next_j();
        const float2 va = ((const float2*)(xb + (size_t)ja * N_FEAT))[lane];
        const float2 vb = ((const float2*)(xb + (size_t)jb * N_FEAT))[lane];
        const float2 vc = ((const float2*)(xb + (size_t)jc * N_FEAT))[lane];
        const float2 vd = ((const float2*)(xb + (size_t)jd * N_FEAT))[lane];
        ax = fmaxf(ax, fmaxf(fmaxf(va.x, vb.x), fmaxf(vc.x, vd.x)));
        ay = fmaxf(ay, fmaxf(fmaxf(va.y, vb.y), fmaxf(vc.y, vd.y)));
    }
    if (m == 0) {   // unreachable (L diagonal is exactly 1.0), kept for fidelity
        const float2 v = ((const float2*)(xb + (size_t)i * N_FEAT))[lane];
        ax = v.x; ay = v.y;
    }
    orow[lane] = make_float2(ax, ay);                   // coalesced 512B row store
}

extern "C" void kernel_launch(void* const* d_in, const int* in_sizes, int n_in,
                              void* d_out, int out_size, void* d_ws, size_t ws_size,
                              hipStream_t stream) {
    const float* x   = (const float*)d_in[0];   // node_features (64,128,128) f32
    const float* L   = (const float*)d_in[1];   // laplacian     (64,128,128) f32
    const int* mol   = (const int*)d_in[2];     // mol_slice     (64,2) i32
    // d_in[3] = l_slice (unused)
    float* out = (float*)d_out;

    dim3 grid(MAX_ATOM / WAVES_PER_BLOCK, B_SIZE);  // (32, 64) = 2048 blocks
    dim3 block(64 * WAVES_PER_BLOCK);               // 256 threads = 4 waves
    GraphPoolMol_kernel<<<grid, block, 0, stream>>>(x, L, mol, out);
}